// Round 15
// baseline (820.250 us; speedup 1.0000x reference)
//
#include <hip/hip_runtime.h>
#include <math.h>

#define BB 1024
#define TT 512
#define FF 32
#define HH 64
#define GG 256   // 4H
#define TC 64
#define NCHUNK (TT/TC)   // 8
#define MB 16            // batch rows per block
#define NBLK 64          // blocks per segment
#define HSTR 72          // ushort row stride in LDS h-planes (144B -> 2-way banks)
#define EPSBN 1e-3f

typedef __attribute__((ext_vector_type(8))) short bf16x8;
typedef __attribute__((ext_vector_type(4))) float f32x4;
typedef __attribute__((ext_vector_type(4))) int   i32x4;
typedef unsigned short ushort_t;

// ---------------- fold1: per-layer BN vectors + attention vector ----------------
__global__ void fold1_kernel(const float* __restrict__ gamma, const float* __restrict__ beta,
                             const float* __restrict__ mean, const float* __restrict__ var,
                             const float* __restrict__ attw, const float* __restrict__ attv,
                             float* __restrict__ s_out, float* __restrict__ ab_out,
                             float* __restrict__ wv_out) {
    int d = threadIdx.x; // 64 threads
    float s = gamma[d] * rsqrtf(var[d] + EPSBN);
    float ab = beta[d] - mean[d] * s;
    float wvr = 0.f;
    for (int e = 0; e < HH; ++e) wvr += attw[d * HH + e] * attv[e];
    s_out[d] = s;
    ab_out[d] = ab;
    wv_out[d] = s * wvr;
}

// ---------------- fold2: fold previous layer's BN into next W, b ----------------
__global__ void fold2_kernel(const float* __restrict__ W, const float* __restrict__ b,
                             const float* __restrict__ s_prev, const float* __restrict__ ab_prev,
                             float* __restrict__ Wp, float* __restrict__ bp) {
    int g = threadIdx.x; // 256 threads
    float bacc = b[g];
    for (int d = 0; d < HH; ++d) {
        float w = W[d * GG + g];
        bacc += ab_prev[d] * w;
        Wp[d * GG + g] = s_prev[d] * w;
    }
    bp[g] = bacc;
}

// ---------------- init per-call state ----------------
__global__ void init_kernel(float* st_h, float* st_c, float* st_acc, float* st_m, float* st_d) {
    int i = blockIdx.x * blockDim.x + threadIdx.x;
    int n = 3 * BB * HH;
    if (i < n) { st_h[i] = 0.f; st_c[i] = 0.f; st_acc[i] = 0.f; }
    if (i < 3 * BB) { st_m[i] = -3.0e38f; st_d[i] = 0.f; }
}

// ---------------- helpers ----------------
__device__ __forceinline__ f32x4 ld4(const float* p) { return *reinterpret_cast<const f32x4*>(p); }
__device__ __forceinline__ void st4(float* p, f32x4 v) { *reinterpret_cast<f32x4*>(p) = v; }
__device__ __forceinline__ bf16x8 ldbf(const ushort_t* p) { return *reinterpret_cast<const bf16x8*>(p); }
__device__ __forceinline__ int cvtpk(float a, float b) {
    int r; asm("v_cvt_pk_bf16_f32 %0, %1, %2" : "=v"(r) : "v"(a), "v"(b)); return r;
}
__device__ __forceinline__ float sigm(float x) { return __fdividef(1.f, 1.f + __expf(-x)); }
#define MFMA(a, b, c) c = __builtin_amdgcn_mfma_f32_16x16x32_bf16(a, b, c, 0, 0, 0)
// In-loop residency pin: redefines the value as opaque each iteration, so the
// compiler cannot re-materialize it from (possibly-aliased) memory. r6/r10's
// pre-loop pins failed because the pinned SSA value died at the first reload.
#define KEEP(x) asm volatile("" : "+v"(x))

// Raw barrier: drain LDS ops (publish visibility) but let vmcnt float across.
__device__ __forceinline__ void step_barrier() {
    asm volatile("s_waitcnt lgkmcnt(0)" ::: "memory");
    __builtin_amdgcn_s_barrier();
    __builtin_amdgcn_sched_barrier(0);
}

// ---------------- prep: fp32 weight matrix -> hi/lo bf16 A-fragments, per-lane layout ----
__global__ void prep_frags(const float* __restrict__ M, int KT, ushort_t* __restrict__ outF) {
    int idx = blockIdx.x * 256 + threadIdx.x;
    int tot = 16 * KT * 512;
    if (idx >= tot) return;
    int e = idx & 7, l = (idx >> 3) & 63, f = idx >> 9;
    int kt = f % KT, gw = f / KT;
    int g = gw & 3, w = gw >> 2;
    int r = l & 15, q = l >> 4;
    int k = 32 * kt + 8 * q + e;
    int col = 64 * g + 16 * w + r;
    float v = M[(size_t)k * GG + col];
    int hb = cvtpk(v, v) & 0xffff;
    float hf = __int_as_float(hb << 16);
    float lo = v - hf;
    int lb = cvtpk(lo, lo) & 0xffff;
    outF[(size_t)(f * 2 + 0) * 512 + l * 8 + e] = (ushort_t)hb;
    outF[(size_t)(f * 2 + 1) * 512 + l * 8 + e] = (ushort_t)lb;
}

// ---------------- prep: fp32 array -> hi/lo bf16 planes (elementwise, vectorized) ----
__global__ void prep_planes(const float* __restrict__ in, ushort_t* __restrict__ hi,
                            ushort_t* __restrict__ lo, int n4) {
    int i = blockIdx.x * 256 + threadIdx.x;
    if (i >= n4) return;
    f32x4 v = reinterpret_cast<const f32x4*>(in)[i];
    int p0 = cvtpk(v[0], v[1]), p1 = cvtpk(v[2], v[3]);
    float a0 = v[0] - __int_as_float(p0 << 16);
    float a1 = v[1] - __int_as_float(p0 & 0xffff0000);
    float a2 = v[2] - __int_as_float(p1 << 16);
    float a3 = v[3] - __int_as_float(p1 & 0xffff0000);
    int q0 = cvtpk(a0, a1), q1 = cvtpk(a2, a3);
    reinterpret_cast<int2*>(hi)[i] = make_int2(p0, p1);
    reinterpret_cast<int2*>(lo)[i] = make_int2(q0, q1);
}

// ---------------- MFMA recurrent kernel: in-loop pinned resident fragments ----------------
struct RecFArgs {
    const ushort_t* xhi[3]; const ushort_t* xlo[3]; long sB[3]; long sT[3]; int K[3];
    const ushort_t* UF[3]; const ushort_t* WF[3]; const float* bias[3];
    ushort_t* Hhi[3]; ushort_t* Hlo[3];   // nullptr -> skip
    float* st_h[3]; float* st_c[3]; float* st_acc[3];
    float* st_m[3]; float* st_d[3];
    const float* wv[3]; const float* abv[3]; const float* sbn[3];
    float* a_out[3];
    int last[3]; int first[3];
};

template<int KT>   // x K-tiles: 1 (K=32, layer1) or 2 (K=64)
__device__ __forceinline__ void rec_body(const RecFArgs& A, const int seg, const int b0,
                                         ushort_t* hbf, float* scoreP) {
    const int tid = threadIdx.x;
    const int w = tid >> 6;
    const int l = tid & 63;
    const int r = l & 15;
    const int q = l >> 4;
    const int cw = w << 4;
    const int grow = b0 + r;

    const bf16x8* __restrict__ UF = reinterpret_cast<const bf16x8*>(A.UF[seg]);
    const bf16x8* __restrict__ WF = reinterpret_cast<const bf16x8*>(A.WF[seg]);
#define LDU(g,kt,p_) UF[(((((w<<2)+(g))*2+(kt))*2)+(p_))*64 + l]
#define LDW(g,kt,p_) WF[(((((w<<2)+(g))*KT+(kt))*2)+(p_))*64 + l]
    bf16x8 uh00=LDU(0,0,0), uh01=LDU(0,1,0), uh10=LDU(1,0,0), uh11=LDU(1,1,0),
           uh20=LDU(2,0,0), uh21=LDU(2,1,0), uh30=LDU(3,0,0), uh31=LDU(3,1,0);
    bf16x8 ul00=LDU(0,0,1), ul01=LDU(0,1,1), ul10=LDU(1,0,1), ul11=LDU(1,1,1),
           ul20=LDU(2,0,1), ul21=LDU(2,1,1), ul30=LDU(3,0,1), ul31=LDU(3,1,1);
    bf16x8 wh00=LDW(0,0,0), wh10=LDW(1,0,0), wh20=LDW(2,0,0), wh30=LDW(3,0,0);
    bf16x8 wl00=LDW(0,0,1), wl10=LDW(1,0,1), wl20=LDW(2,0,1), wl30=LDW(3,0,1);
    bf16x8 wh01{}, wh11{}, wh21{}, wh31{}, wl01{}, wl11{}, wl21{}, wl31{};
    if constexpr (KT == 2) {
        wh01=LDW(0,1,0); wh11=LDW(1,1,0); wh21=LDW(2,1,0); wh31=LDW(3,1,0);
        wl01=LDW(0,1,1); wl11=LDW(1,1,1); wl21=LDW(2,1,1); wl31=LDW(3,1,1);
    }

    f32x4 bias40 = ld4(A.bias[seg] +   0 + cw + 4 * q);
    f32x4 bias41 = ld4(A.bias[seg] +  64 + cw + 4 * q);
    f32x4 bias42 = ld4(A.bias[seg] + 128 + cw + 4 * q);
    f32x4 bias43 = ld4(A.bias[seg] + 192 + cw + 4 * q);
    f32x4 wv4 = ld4(A.wv[seg] + cw + 4 * q);      // own 4 units only

    f32x4 c4   = ld4(A.st_c[seg]   + (size_t)grow * HH + cw + 4 * q);
    f32x4 h4   = ld4(A.st_h[seg]   + (size_t)grow * HH + cw + 4 * q);
    f32x4 acc4 = ld4(A.st_acc[seg] + (size_t)grow * HH + cw + 4 * q);
    float m_b = A.st_m[seg][grow];
    float d_b = A.st_d[seg][grow];

    int2 hs_hi, hs_lo;     // h planes of previous step (deferred global store)
    auto publish = [&](int slot, f32x4 hv) {
        int p0 = cvtpk(hv[0], hv[1]), p1 = cvtpk(hv[2], hv[3]);
        float a0 = hv[0] - __int_as_float(p0 << 16);
        float a1 = hv[1] - __int_as_float(p0 & 0xffff0000);
        float a2 = hv[2] - __int_as_float(p1 << 16);
        float a3 = hv[3] - __int_as_float(p1 & 0xffff0000);
        int q0 = cvtpk(a0, a1), q1 = cvtpk(a2, a3);
        hs_hi = make_int2(p0, p1); hs_lo = make_int2(q0, q1);
        *reinterpret_cast<int2*>(hbf + ((slot * 2 + 0) * 16 + r) * HSTR + cw + 4 * q) = hs_hi;
        *reinterpret_cast<int2*>(hbf + ((slot * 2 + 1) * 16 + r) * HSTR + cw + 4 * q) = hs_lo;
        float part = hv[0] * wv4[0];
        part = fmaf(hv[1], wv4[1], part);
        part = fmaf(hv[2], wv4[2], part);
        part = fmaf(hv[3], wv4[3], part);
        part += __shfl_xor(part, 16);
        part += __shfl_xor(part, 32);
        if (q == 0) scoreP[(slot * 4 + w) * 16 + r] = part;
    };

    publish(0, h4);   // carried h -> slot 0 (consumed at t=0)

    const ushort_t* __restrict__ xhib = A.xhi[seg] + (size_t)grow * A.sB[seg];
    const ushort_t* __restrict__ xlob = A.xlo[seg] + (size_t)grow * A.sB[seg];
    const long sT = A.sT[seg];

    auto xload = [&](int t, bf16x8& h0, bf16x8& l0, bf16x8& h1, bf16x8& l1) {
        const ushort_t* ph = xhib + (size_t)t * sT + 8 * q;
        const ushort_t* pl = xlob + (size_t)t * sT + 8 * q;
        h0 = ldbf(ph); l0 = ldbf(pl);
        if constexpr (KT == 2) { h1 = ldbf(ph + 32); l1 = ldbf(pl + 32); }
    };

    // ZX(t) = bias + W.x(t), 3-term (same accumulation order as r14)
    f32x4 ZX0, ZX1, ZX2, ZX3;
    auto buildZX = [&](bf16x8 xh0, bf16x8 xl0, bf16x8 xh1, bf16x8 xl1) {
        ZX0 = bias40; ZX1 = bias41; ZX2 = bias42; ZX3 = bias43;
        MFMA(wh00, xh0, ZX0); MFMA(wh00, xl0, ZX0); MFMA(wl00, xh0, ZX0);
        if constexpr (KT == 2) { MFMA(wh01, xh1, ZX0); MFMA(wh01, xl1, ZX0); MFMA(wl01, xh1, ZX0); }
        MFMA(wh10, xh0, ZX1); MFMA(wh10, xl0, ZX1); MFMA(wl10, xh0, ZX1);
        if constexpr (KT == 2) { MFMA(wh11, xh1, ZX1); MFMA(wh11, xl1, ZX1); MFMA(wl11, xh1, ZX1); }
        MFMA(wh20, xh0, ZX2); MFMA(wh20, xl0, ZX2); MFMA(wl20, xh0, ZX2);
        if constexpr (KT == 2) { MFMA(wh21, xh1, ZX2); MFMA(wh21, xl1, ZX2); MFMA(wl21, xh1, ZX2); }
        MFMA(wh30, xh0, ZX3); MFMA(wh30, xl0, ZX3); MFMA(wl30, xh0, ZX3);
        if constexpr (KT == 2) { MFMA(wh31, xh1, ZX3); MFMA(wh31, xl1, ZX3); MFMA(wl31, xh1, ZX3); }
    };

    // prologue: ZX(0) from x(0); prefetch x(1) -> xc, x(2) -> xn
    {
        bf16x8 x0h0, x0l0, x0h1{}, x0l1{};
        xload(0, x0h0, x0l0, x0h1, x0l1);
        buildZX(x0h0, x0l0, x0h1, x0l1);
    }
    bf16x8 xc_h0, xc_l0, xc_h1{}, xc_l1{};
    bf16x8 xn_h0, xn_l0, xn_h1{}, xn_l1{};
    xload(1 < TC ? 1 : TC - 1, xc_h0, xc_l0, xc_h1, xc_l1);
    xload(2 < TC ? 2 : TC - 1, xn_h0, xn_l0, xn_h1, xn_l1);
    step_barrier();

    const bool first = A.first[seg] != 0;
    ushort_t* __restrict__ Hhi = A.Hhi[seg];
    ushort_t* __restrict__ Hlo = A.Hlo[seg];

#pragma unroll 2
    for (int t = 0; t < TC; ++t) {
        // ---- residency pins: force all static operands to live in VGPRs across
        // the backedge (the compiler otherwise re-loads them every iteration
        // because the Hhi/hbf stores may alias the fragment buffers) ----
        KEEP(uh00); KEEP(uh01); KEEP(uh10); KEEP(uh11);
        KEEP(uh20); KEEP(uh21); KEEP(uh30); KEEP(uh31);
        KEEP(ul00); KEEP(ul01); KEEP(ul10); KEEP(ul11);
        KEEP(ul20); KEEP(ul21); KEEP(ul30); KEEP(ul31);
        KEEP(wh00); KEEP(wh10); KEEP(wh20); KEEP(wh30);
        KEEP(wl00); KEEP(wl10); KEEP(wl20); KEEP(wl30);
        if constexpr (KT == 2) {
            KEEP(wh01); KEEP(wh11); KEEP(wh21); KEEP(wh31);
            KEEP(wl01); KEEP(wl11); KEEP(wl21); KEEP(wl31);
        }
        KEEP(bias40); KEEP(bias41); KEEP(bias42); KEEP(bias43);
        KEEP(wv4);

        const int pr = t & 1;
        // deferred Hout store of h_{t-1} (vmcnt floats across barriers)
        if (Hhi && t > 0) {
            size_t ho = (size_t)grow * (TC * HH) + (size_t)(t - 1) * HH + cw + 4 * q;
            *reinterpret_cast<int2*>(Hhi + ho) = hs_hi;
            *reinterpret_cast<int2*>(Hlo + ho) = hs_lo;
        }
        // attention merge for h_{t-1}
        float sc = scoreP[(pr * 4 + q) * 16 + r];
        sc += __shfl_xor(sc, 16);
        sc += __shfl_xor(sc, 32);
        if (!(first && t == 0)) {
            float mn = fmaxf(m_b, sc);
            float corr = __expf(m_b - mn);
            float p = __expf(sc - mn);
            d_b = d_b * corr + p;
            acc4 = acc4 * corr + p * h4;
            m_b = mn;
        }

        // B-fragments of h_{t-1}: direct bf16 LDS reads
        const ushort_t* hbh = hbf + (pr * 2 + 0) * 16 * HSTR + r * HSTR;
        const ushort_t* hbl = hbf + (pr * 2 + 1) * 16 * HSTR + r * HSTR;
        bf16x8 bh0 = ldbf(hbh + 8 * q);
        bf16x8 bh1 = ldbf(hbh + 32 + 8 * q);
        bf16x8 bl0 = ldbf(hbl + 8 * q);
        bf16x8 bl1 = ldbf(hbl + 32 + 8 * q);

        // C = ZX(t) (precomputed), then U-MFMAs (6/gate, same order as r14)
        f32x4 C0 = ZX0, C1 = ZX1, C2 = ZX2, C3 = ZX3;
        MFMA(uh00, bh0, C0); MFMA(uh00, bl0, C0); MFMA(ul00, bh0, C0);
        MFMA(uh01, bh1, C0); MFMA(uh01, bl1, C0); MFMA(ul01, bh1, C0);
        MFMA(uh10, bh0, C1); MFMA(uh10, bl0, C1); MFMA(ul10, bh0, C1);
        MFMA(uh11, bh1, C1); MFMA(uh11, bl1, C1); MFMA(ul11, bh1, C1);
        MFMA(uh20, bh0, C2); MFMA(uh20, bl0, C2); MFMA(ul20, bh0, C2);
        MFMA(uh21, bh1, C2); MFMA(uh21, bl1, C2); MFMA(ul21, bh1, C2);
        MFMA(uh30, bh0, C3); MFMA(uh30, bl0, C3); MFMA(ul30, bh0, C3);
        MFMA(uh31, bh1, C3); MFMA(uh31, bl1, C3); MFMA(ul31, bh1, C3);

        // ZX(t+1) from xc = x(t+1): independent of h, fills U-chain stalls
        buildZX(xc_h0, xc_l0, xc_h1, xc_l1);
        // rotate prefetch: xc <- xn = x(t+2); issue load x(t+3) -> xn
        xc_h0 = xn_h0; xc_l0 = xn_l0;
        if constexpr (KT == 2) { xc_h1 = xn_h1; xc_l1 = xn_l1; }
        { int tn = (t + 3 < TC) ? t + 3 : TC - 1; xload(tn, xn_h0, xn_l0, xn_h1, xn_l1); }

        // activation + state update
#pragma unroll
        for (int i = 0; i < 4; ++i) {
            float zi = sigm(C0[i]);
            float zf = sigm(C1[i]);
            float zg = fmaxf(C2[i], 0.f);
            float zo = sigm(C3[i]);
            c4[i] = fmaf(zf, c4[i], zi * zg);
            h4[i] = zo * fmaxf(c4[i], 0.f);
        }
        publish(pr ^ 1, h4);
        step_barrier();
    }

    // post-loop: final Hout store of h_{TC-1}
    if (Hhi) {
        size_t ho = (size_t)grow * (TC * HH) + (size_t)(TC - 1) * HH + cw + 4 * q;
        *reinterpret_cast<int2*>(Hhi + ho) = hs_hi;
        *reinterpret_cast<int2*>(Hlo + ho) = hs_lo;
    }
    // last chunk: merge h_{TC-1}'s score (slot 0, TC even) and emit attention output
    if (A.last[seg]) {
        float sc = scoreP[(0 * 4 + q) * 16 + r];
        sc += __shfl_xor(sc, 16);
        sc += __shfl_xor(sc, 32);
        float mn = fmaxf(m_b, sc);
        float corr = __expf(m_b - mn);
        float p = __expf(sc - mn);
        d_b = d_b * corr + p;
        acc4 = acc4 * corr + p * h4;
        m_b = mn;
        f32x4 sb = ld4(A.sbn[seg] + cw + 4 * q);
        f32x4 ab = ld4(A.abv[seg] + cw + 4 * q);
        f32x4 res;
#pragma unroll
        for (int i = 0; i < 4; ++i)
            res[i] = sb[i] * __fdividef(acc4[i], d_b) + ab[i];
        st4(A.a_out[seg] + (size_t)grow * HH + cw + 4 * q, res);
    }
    st4(A.st_c[seg]   + (size_t)grow * HH + cw + 4 * q, c4);
    st4(A.st_h[seg]   + (size_t)grow * HH + cw + 4 * q, h4);
    st4(A.st_acc[seg] + (size_t)grow * HH + cw + 4 * q, acc4);
    if (w == 0 && q == 0) { A.st_m[seg][grow] = m_b; A.st_d[seg][grow] = d_b; }
#undef LDU
#undef LDW
}

__global__ __launch_bounds__(256, 1) void rec_mfma(RecFArgs A) {
    __shared__ ushort_t hbf[2 * 2 * 16 * HSTR];   // 9.2 KB: parity x {hi,lo} x [16][72]
    __shared__ float scoreP[2 * 4 * 16];          // 512 B: parity x wave x row
    const int seg = blockIdx.x >> 6;              // NBLK = 64
    const int b0 = (blockIdx.x & (NBLK - 1)) << 4;
    if (A.K[seg] == 32) rec_body<1>(A, seg, b0, hbf, scoreP);
    else                rec_body<2>(A, seg, b0, hbf, scoreP);
}

// ---------------- final: out[b] = db + sum_{l,j} a[l][b][j]*dw[l*64+j] ----------------
__global__ void final_kernel(const float* __restrict__ a, const float* __restrict__ dw,
                             const float* __restrict__ db, float* __restrict__ out) {
    int b = blockIdx.x * blockDim.x + threadIdx.x;
    if (b >= BB) return;
    float acc = db[0];
    for (int l = 0; l < 3; ++l)
        for (int j = 0; j < HH; ++j)
            acc += a[(l * BB + b) * HH + j] * dw[l * HH + j];
    out[b] = acc;
}

extern "C" void kernel_launch(void* const* d_in, const int* in_sizes, int n_in,
                              void* d_out, int out_size, void* d_ws, size_t ws_size,
                              hipStream_t stream) {
    (void)in_sizes; (void)n_in; (void)out_size; (void)ws_size;
    const float* x = (const float*)d_in[0];
    const float* w[3]    = {(const float*)d_in[1],  (const float*)d_in[10], (const float*)d_in[19]};
    const float* uu[3]   = {(const float*)d_in[2],  (const float*)d_in[11], (const float*)d_in[20]};
    const float* bi[3]   = {(const float*)d_in[3],  (const float*)d_in[12], (const float*)d_in[21]};
    const float* gam[3]  = {(const float*)d_in[4],  (const float*)d_in[13], (const float*)d_in[22]};
    const float* bet[3]  = {(const float*)d_in[5],  (const float*)d_in[14], (const float*)d_in[23]};
    const float* mea[3]  = {(const float*)d_in[6],  (const float*)d_in[15], (const float*)d_in[24]};
    const float* var[3]  = {(const float*)d_in[7],  (const float*)d_in[16], (const float*)d_in[25]};
    const float* atw[3]  = {(const float*)d_in[8],  (const float*)d_in[17], (const float*)d_in[26]};
    const float* atv[3]  = {(const float*)d_in[9],  (const float*)d_in[18], (const float*)d_in[27]};
    const float* dw = (const float*)d_in[28];
    const float* db = (const float*)d_in[29];

    float* ws = (float*)d_ws;
    size_t off = 0;
    // cross-layer h planes (bf16 hi/lo), parity double-buffered
    ushort_t* Hhi[2][2]; ushort_t* Hlo[2][2];
    for (int l = 0; l < 2; ++l)
        for (int p = 0; p < 2; ++p) {
            Hhi[l][p] = (ushort_t*)(ws + off); off += (size_t)BB * TC * HH / 2;
            Hlo[l][p] = (ushort_t*)(ws + off); off += (size_t)BB * TC * HH / 2;
        }
    // layer-1 input planes (bf16 hi/lo)
    ushort_t* Xhi = (ushort_t*)(ws + off); off += (size_t)BB * TT * FF / 2;
    ushort_t* Xlo = (ushort_t*)(ws + off); off += (size_t)BB * TT * FF / 2;
    float* st_h  = ws + off; off += 3 * BB * HH;
    float* st_c  = ws + off; off += 3 * BB * HH;
    float* st_ac = ws + off; off += 3 * BB * HH;
    float* st_m  = ws + off; off += 3 * BB;
    float* st_d  = ws + off; off += 3 * BB;
    float* s_ws  = ws + off; off += 3 * HH;
    float* ab_ws = ws + off; off += 3 * HH;
    float* wv_ws = ws + off; off += 3 * HH;
    float* W2p   = ws + off; off += HH * GG;
    float* W3p   = ws + off; off += HH * GG;
    float* b2p   = ws + off; off += GG;
    float* b3p   = ws + off; off += GG;
    float* a_ws  = ws + off; off += 3 * BB * HH;
    ushort_t* UFb[3]; ushort_t* WFb[3];
    for (int l = 0; l < 3; ++l) { UFb[l] = (ushort_t*)(ws + off); off += 16384; }  // 64KB each
    for (int l = 0; l < 3; ++l) { WFb[l] = (ushort_t*)(ws + off); off += 16384; }

    for (int l = 0; l < 3; ++l)
        fold1_kernel<<<1, 64, 0, stream>>>(gam[l], bet[l], mea[l], var[l], atw[l], atv[l],
                                           s_ws + l * HH, ab_ws + l * HH, wv_ws + l * HH);
    fold2_kernel<<<1, 256, 0, stream>>>(w[1], bi[1], s_ws + 0 * HH, ab_ws + 0 * HH, W2p, b2p);
    fold2_kernel<<<1, 256, 0, stream>>>(w[2], bi[2], s_ws + 1 * HH, ab_ws + 1 * HH, W3p, b3p);
    init_kernel<<<(3 * BB * HH + 255) / 256, 256, 0, stream>>>(st_h, st_c, st_ac, st_m, st_d);

    // pre-build bf16 weight fragments and x planes
    for (int l = 0; l < 3; ++l)
        prep_frags<<<64, 256, 0, stream>>>(uu[l], 2, UFb[l]);
    prep_frags<<<32, 256, 0, stream>>>(w[0], 1, WFb[0]);
    prep_frags<<<64, 256, 0, stream>>>(W2p, 2, WFb[1]);
    prep_frags<<<64, 256, 0, stream>>>(W3p, 2, WFb[2]);
    {
        int n4 = BB * TT * FF / 4;
        prep_planes<<<(n4 + 255) / 256, 256, 0, stream>>>(x, Xhi, Xlo, n4);
    }

    const float* bl[3] = {bi[0], b2p, b3p};

    // software pipeline: at step s, layer l processes chunk s-l
    for (int s = 0; s <= NCHUNK - 1 + 2; ++s) {
        RecFArgs ra;
        int nseg = 0;
        for (int l = 0; l < 3; ++l) {
            int cpos = s - l;
            if (cpos < 0 || cpos >= NCHUNK) continue;
            if (l == 0) {
                ra.xhi[nseg] = Xhi + (size_t)cpos * TC * FF;
                ra.xlo[nseg] = Xlo + (size_t)cpos * TC * FF;
                ra.sB[nseg] = (long)TT * FF;
                ra.sT[nseg] = FF;
                ra.K[nseg] = 32;
            } else {
                int par = (s & 1) ^ 1;               // written by layer l-1 at step s-1
                ra.xhi[nseg] = Hhi[l - 1][par];
                ra.xlo[nseg] = Hlo[l - 1][par];
                ra.sB[nseg] = (long)TC * HH;
                ra.sT[nseg] = HH;
                ra.K[nseg] = 64;
            }
            ra.UF[nseg] = UFb[l]; ra.WF[nseg] = WFb[l]; ra.bias[nseg] = bl[l];
            ra.Hhi[nseg] = (l < 2) ? Hhi[l][s & 1] : (ushort_t*)0;
            ra.Hlo[nseg] = (l < 2) ? Hlo[l][s & 1] : (ushort_t*)0;
            ra.st_h[nseg] = st_h + l * BB * HH;
            ra.st_c[nseg] = st_c + l * BB * HH;
            ra.st_acc[nseg] = st_ac + l * BB * HH;
            ra.st_m[nseg] = st_m + l * BB;
            ra.st_d[nseg] = st_d + l * BB;
            ra.wv[nseg]  = wv_ws + l * HH;
            ra.abv[nseg] = ab_ws + l * HH;
            ra.sbn[nseg] = s_ws + l * HH;
            ra.a_out[nseg] = a_ws + l * BB * HH;
            ra.last[nseg]  = (cpos == NCHUNK - 1) ? 1 : 0;
            ra.first[nseg] = (cpos == 0) ? 1 : 0;
            ++nseg;
        }
        if (!nseg) continue;
        rec_mfma<<<nseg * NBLK, 256, 0, stream>>>(ra);
    }
    final_kernel<<<(BB + 255) / 256, 256, 0, stream>>>(a_ws, dw, db, (float*)d_out);
}

// Round 16
// 742.321 us; speedup vs baseline: 1.1050x; 1.1050x over previous
//
#include <hip/hip_runtime.h>
#include <math.h>

#define BB 1024
#define TT 512
#define FF 32
#define HH 64
#define GG 256   // 4H
#define TC 64
#define NCHUNK (TT/TC)   // 8
#define MB 16            // batch rows per block
#define NBLK 64          // blocks per segment
#define HSTR 72          // ushort row stride in LDS h-planes (144B -> 2-way banks)
#define SSTR 20          // float row stride in scoreP (80B -> 2-way banks, 16B aligned)
#define EPSBN 1e-3f

typedef __attribute__((ext_vector_type(8))) short bf16x8;
typedef __attribute__((ext_vector_type(4))) float f32x4;
typedef __attribute__((ext_vector_type(4))) int   i32x4;
typedef unsigned short ushort_t;

// ---------------- fold1: per-layer BN vectors + attention vector ----------------
__global__ void fold1_kernel(const float* __restrict__ gamma, const float* __restrict__ beta,
                             const float* __restrict__ mean, const float* __restrict__ var,
                             const float* __restrict__ attw, const float* __restrict__ attv,
                             float* __restrict__ s_out, float* __restrict__ ab_out,
                             float* __restrict__ wv_out) {
    int d = threadIdx.x; // 64 threads
    float s = gamma[d] * rsqrtf(var[d] + EPSBN);
    float ab = beta[d] - mean[d] * s;
    float wvr = 0.f;
    for (int e = 0; e < HH; ++e) wvr += attw[d * HH + e] * attv[e];
    s_out[d] = s;
    ab_out[d] = ab;
    wv_out[d] = s * wvr;
}

// ---------------- fold2: fold previous layer's BN into next W, b ----------------
__global__ void fold2_kernel(const float* __restrict__ W, const float* __restrict__ b,
                             const float* __restrict__ s_prev, const float* __restrict__ ab_prev,
                             float* __restrict__ Wp, float* __restrict__ bp) {
    int g = threadIdx.x; // 256 threads
    float bacc = b[g];
    for (int d = 0; d < HH; ++d) {
        float w = W[d * GG + g];
        bacc += ab_prev[d] * w;
        Wp[d * GG + g] = s_prev[d] * w;
    }
    bp[g] = bacc;
}

// ---------------- init per-call state ----------------
__global__ void init_kernel(float* st_h, float* st_c, float* st_acc, float* st_m, float* st_d) {
    int i = blockIdx.x * blockDim.x + threadIdx.x;
    int n = 3 * BB * HH;
    if (i < n) { st_h[i] = 0.f; st_c[i] = 0.f; st_acc[i] = 0.f; }
    if (i < 3 * BB) { st_m[i] = -3.0e38f; st_d[i] = 0.f; }
}

// ---------------- helpers ----------------
__device__ __forceinline__ f32x4 ld4(const float* p) { return *reinterpret_cast<const f32x4*>(p); }
__device__ __forceinline__ void st4(float* p, f32x4 v) { *reinterpret_cast<f32x4*>(p) = v; }
__device__ __forceinline__ bf16x8 ldbf(const ushort_t* p) { return *reinterpret_cast<const bf16x8*>(p); }
__device__ __forceinline__ int cvtpk(float a, float b) {
    int r; asm("v_cvt_pk_bf16_f32 %0, %1, %2" : "=v"(r) : "v"(a), "v"(b)); return r;
}
__device__ __forceinline__ float sigm(float x) { return __fdividef(1.f, 1.f + __expf(-x)); }
#define MFMA(a, b, c) c = __builtin_amdgcn_mfma_f32_16x16x32_bf16(a, b, c, 0, 0, 0)

// Raw barrier: drain LDS ops (publish visibility) but let vmcnt float across.
__device__ __forceinline__ void step_barrier() {
    asm volatile("s_waitcnt lgkmcnt(0)" ::: "memory");
    __builtin_amdgcn_s_barrier();
    __builtin_amdgcn_sched_barrier(0);
}

// ---------------- prep: fp32 weight matrix -> hi/lo bf16 A-fragments, per-lane layout ----
__global__ void prep_frags(const float* __restrict__ M, int KT, ushort_t* __restrict__ outF) {
    int idx = blockIdx.x * 256 + threadIdx.x;
    int tot = 16 * KT * 512;
    if (idx >= tot) return;
    int e = idx & 7, l = (idx >> 3) & 63, f = idx >> 9;
    int kt = f % KT, gw = f / KT;
    int g = gw & 3, w = gw >> 2;
    int r = l & 15, q = l >> 4;
    int k = 32 * kt + 8 * q + e;
    int col = 64 * g + 16 * w + r;
    float v = M[(size_t)k * GG + col];
    int hb = cvtpk(v, v) & 0xffff;
    float hf = __int_as_float(hb << 16);
    float lo = v - hf;
    int lb = cvtpk(lo, lo) & 0xffff;
    outF[(size_t)(f * 2 + 0) * 512 + l * 8 + e] = (ushort_t)hb;
    outF[(size_t)(f * 2 + 1) * 512 + l * 8 + e] = (ushort_t)lb;
}

// ---------------- prep: fp32 array -> hi/lo bf16 planes (elementwise, vectorized) ----
__global__ void prep_planes(const float* __restrict__ in, ushort_t* __restrict__ hi,
                            ushort_t* __restrict__ lo, int n4) {
    int i = blockIdx.x * 256 + threadIdx.x;
    if (i >= n4) return;
    f32x4 v = reinterpret_cast<const f32x4*>(in)[i];
    int p0 = cvtpk(v[0], v[1]), p1 = cvtpk(v[2], v[3]);
    float a0 = v[0] - __int_as_float(p0 << 16);
    float a1 = v[1] - __int_as_float(p0 & 0xffff0000);
    float a2 = v[2] - __int_as_float(p1 << 16);
    float a3 = v[3] - __int_as_float(p1 & 0xffff0000);
    int q0 = cvtpk(a0, a1), q1 = cvtpk(a2, a3);
    reinterpret_cast<int2*>(hi)[i] = make_int2(p0, p1);
    reinterpret_cast<int2*>(lo)[i] = make_int2(q0, q1);
}

// ---------------- MFMA recurrent kernel: shfl-free score exchange ----------------
// Block = 16 rows, 4 waves. Wave w owns gate-cols {64g+16w+..}; lane (r,q) holds all 4
// gates of (row r, units 16w+4q..+4) -> in-lane c/h update. h published as bf16 hi/lo
// planes in LDS; B-fragments read directly. Attention score: each lane writes its raw
// 4-unit partial to scoreP[slot][r][w*4+q] (no shfl); consumer reads the row's 16
// partials as 4 parallel b128 + 6 adds, issued at step top so latency hides under MFMAs.
struct RecFArgs {
    const ushort_t* xhi[3]; const ushort_t* xlo[3]; long sB[3]; long sT[3]; int K[3];
    const ushort_t* UF[3]; const ushort_t* WF[3]; const float* bias[3];
    ushort_t* Hhi[3]; ushort_t* Hlo[3];   // nullptr -> skip
    float* st_h[3]; float* st_c[3]; float* st_acc[3];
    float* st_m[3]; float* st_d[3];
    const float* wv[3]; const float* abv[3]; const float* sbn[3];
    float* a_out[3];
    int last[3]; int first[3];
};

template<int KT>   // x K-tiles: 1 (K=32, layer1) or 2 (K=64)
__device__ __forceinline__ void rec_body(const RecFArgs& A, const int seg, const int b0,
                                         ushort_t* hbf, float* scoreP) {
    const int tid = threadIdx.x;
    const int w = tid >> 6;
    const int l = tid & 63;
    const int r = l & 15;
    const int q = l >> 4;
    const int cw = w << 4;
    const int grow = b0 + r;

    const bf16x8* __restrict__ UF = reinterpret_cast<const bf16x8*>(A.UF[seg]);
    const bf16x8* __restrict__ WF = reinterpret_cast<const bf16x8*>(A.WF[seg]);
#define LDU(g,kt,p_) UF[(((((w<<2)+(g))*2+(kt))*2)+(p_))*64 + l]
#define LDW(g,kt,p_) WF[(((((w<<2)+(g))*KT+(kt))*2)+(p_))*64 + l]
    bf16x8 uh00=LDU(0,0,0), uh01=LDU(0,1,0), uh10=LDU(1,0,0), uh11=LDU(1,1,0),
           uh20=LDU(2,0,0), uh21=LDU(2,1,0), uh30=LDU(3,0,0), uh31=LDU(3,1,0);
    bf16x8 ul00=LDU(0,0,1), ul01=LDU(0,1,1), ul10=LDU(1,0,1), ul11=LDU(1,1,1),
           ul20=LDU(2,0,1), ul21=LDU(2,1,1), ul30=LDU(3,0,1), ul31=LDU(3,1,1);
    bf16x8 wh00=LDW(0,0,0), wh10=LDW(1,0,0), wh20=LDW(2,0,0), wh30=LDW(3,0,0);
    bf16x8 wl00=LDW(0,0,1), wl10=LDW(1,0,1), wl20=LDW(2,0,1), wl30=LDW(3,0,1);
    bf16x8 wh01{}, wh11{}, wh21{}, wh31{}, wl01{}, wl11{}, wl21{}, wl31{};
    if constexpr (KT == 2) {
        wh01=LDW(0,1,0); wh11=LDW(1,1,0); wh21=LDW(2,1,0); wh31=LDW(3,1,0);
        wl01=LDW(0,1,1); wl11=LDW(1,1,1); wl21=LDW(2,1,1); wl31=LDW(3,1,1);
    }

    f32x4 bias40 = ld4(A.bias[seg] +   0 + cw + 4 * q);
    f32x4 bias41 = ld4(A.bias[seg] +  64 + cw + 4 * q);
    f32x4 bias42 = ld4(A.bias[seg] + 128 + cw + 4 * q);
    f32x4 bias43 = ld4(A.bias[seg] + 192 + cw + 4 * q);
    f32x4 wv4 = ld4(A.wv[seg] + cw + 4 * q);      // own 4 units only

    f32x4 c4   = ld4(A.st_c[seg]   + (size_t)grow * HH + cw + 4 * q);
    f32x4 h4   = ld4(A.st_h[seg]   + (size_t)grow * HH + cw + 4 * q);
    f32x4 acc4 = ld4(A.st_acc[seg] + (size_t)grow * HH + cw + 4 * q);
    float m_b = A.st_m[seg][grow];
    float d_b = A.st_d[seg][grow];

    int2 hs_hi, hs_lo;     // h planes of previous step (deferred global store)
    // publish: convert own slice -> LDS planes + raw score partial (no shfl)
    auto publish = [&](int slot, f32x4 hv) {
        int p0 = cvtpk(hv[0], hv[1]), p1 = cvtpk(hv[2], hv[3]);
        float a0 = hv[0] - __int_as_float(p0 << 16);
        float a1 = hv[1] - __int_as_float(p0 & 0xffff0000);
        float a2 = hv[2] - __int_as_float(p1 << 16);
        float a3 = hv[3] - __int_as_float(p1 & 0xffff0000);
        int q0 = cvtpk(a0, a1), q1 = cvtpk(a2, a3);
        hs_hi = make_int2(p0, p1); hs_lo = make_int2(q0, q1);
        *reinterpret_cast<int2*>(hbf + ((slot * 2 + 0) * 16 + r) * HSTR + cw + 4 * q) = hs_hi;
        *reinterpret_cast<int2*>(hbf + ((slot * 2 + 1) * 16 + r) * HSTR + cw + 4 * q) = hs_lo;
        float part = hv[0] * wv4[0];
        part = fmaf(hv[1], wv4[1], part);
        part = fmaf(hv[2], wv4[2], part);
        part = fmaf(hv[3], wv4[3], part);
        scoreP[(slot * 16 + r) * SSTR + (w << 2) + q] = part;
    };

    publish(0, h4);   // carried h -> slot 0 (consumed at t=0)

    const ushort_t* __restrict__ xhib = A.xhi[seg] + (size_t)grow * A.sB[seg];
    const ushort_t* __restrict__ xlob = A.xlo[seg] + (size_t)grow * A.sB[seg];
    const long sT = A.sT[seg];

    auto xload = [&](int t, bf16x8& h0, bf16x8& l0, bf16x8& h1, bf16x8& l1) {
        const ushort_t* ph = xhib + (size_t)t * sT + 8 * q;
        const ushort_t* pl = xlob + (size_t)t * sT + 8 * q;
        h0 = ldbf(ph); l0 = ldbf(pl);
        if constexpr (KT == 2) { h1 = ldbf(ph + 32); l1 = ldbf(pl + 32); }
    };

    // ZX(t) = bias + W.x(t), 3-term (same accumulation order as r14)
    f32x4 ZX0, ZX1, ZX2, ZX3;
    auto buildZX = [&](bf16x8 xh0, bf16x8 xl0, bf16x8 xh1, bf16x8 xl1) {
        ZX0 = bias40; ZX1 = bias41; ZX2 = bias42; ZX3 = bias43;
        MFMA(wh00, xh0, ZX0); MFMA(wh00, xl0, ZX0); MFMA(wl00, xh0, ZX0);
        if constexpr (KT == 2) { MFMA(wh01, xh1, ZX0); MFMA(wh01, xl1, ZX0); MFMA(wl01, xh1, ZX0); }
        MFMA(wh10, xh0, ZX1); MFMA(wh10, xl0, ZX1); MFMA(wl10, xh0, ZX1);
        if constexpr (KT == 2) { MFMA(wh11, xh1, ZX1); MFMA(wh11, xl1, ZX1); MFMA(wl11, xh1, ZX1); }
        MFMA(wh20, xh0, ZX2); MFMA(wh20, xl0, ZX2); MFMA(wl20, xh0, ZX2);
        if constexpr (KT == 2) { MFMA(wh21, xh1, ZX2); MFMA(wh21, xl1, ZX2); MFMA(wl21, xh1, ZX2); }
        MFMA(wh30, xh0, ZX3); MFMA(wh30, xl0, ZX3); MFMA(wl30, xh0, ZX3);
        if constexpr (KT == 2) { MFMA(wh31, xh1, ZX3); MFMA(wh31, xl1, ZX3); MFMA(wl31, xh1, ZX3); }
    };

    // prologue: ZX(0) from x(0); prefetch x(1) -> xc, x(2) -> xn
    {
        bf16x8 x0h0, x0l0, x0h1{}, x0l1{};
        xload(0, x0h0, x0l0, x0h1, x0l1);
        buildZX(x0h0, x0l0, x0h1, x0l1);
    }
    bf16x8 xc_h0, xc_l0, xc_h1{}, xc_l1{};
    bf16x8 xn_h0, xn_l0, xn_h1{}, xn_l1{};
    xload(1 < TC ? 1 : TC - 1, xc_h0, xc_l0, xc_h1, xc_l1);
    xload(2 < TC ? 2 : TC - 1, xn_h0, xn_l0, xn_h1, xn_l1);
    step_barrier();

    const bool first = A.first[seg] != 0;
    ushort_t* __restrict__ Hhi = A.Hhi[seg];
    ushort_t* __restrict__ Hlo = A.Hlo[seg];

#pragma unroll 2
    for (int t = 0; t < TC; ++t) {
        const int pr = t & 1;
        // --- issue ALL LDS reads up front: score partials + B-fragments ---
        const float* sp = scoreP + (pr * 16 + r) * SSTR;
        f32x4 s0 = ld4(sp), s1 = ld4(sp + 4), s2 = ld4(sp + 8), s3 = ld4(sp + 12);
        const ushort_t* hbh = hbf + (pr * 2 + 0) * 16 * HSTR + r * HSTR;
        const ushort_t* hbl = hbf + (pr * 2 + 1) * 16 * HSTR + r * HSTR;
        bf16x8 bh0 = ldbf(hbh + 8 * q);
        bf16x8 bh1 = ldbf(hbh + 32 + 8 * q);
        bf16x8 bl0 = ldbf(hbl + 8 * q);
        bf16x8 bl1 = ldbf(hbl + 32 + 8 * q);

        // deferred Hout store of h_{t-1} (vmcnt floats across barriers)
        if (Hhi && t > 0) {
            size_t ho = (size_t)grow * (TC * HH) + (size_t)(t - 1) * HH + cw + 4 * q;
            *reinterpret_cast<int2*>(Hhi + ho) = hs_hi;
            *reinterpret_cast<int2*>(Hlo + ho) = hs_lo;
        }

        // C = ZX(t) (precomputed), then U-MFMAs (6/gate, same order as r14)
        f32x4 C0 = ZX0, C1 = ZX1, C2 = ZX2, C3 = ZX3;
        MFMA(uh00, bh0, C0); MFMA(uh00, bl0, C0); MFMA(ul00, bh0, C0);
        MFMA(uh01, bh1, C0); MFMA(uh01, bl1, C0); MFMA(ul01, bh1, C0);
        MFMA(uh10, bh0, C1); MFMA(uh10, bl0, C1); MFMA(ul10, bh0, C1);
        MFMA(uh11, bh1, C1); MFMA(uh11, bl1, C1); MFMA(ul11, bh1, C1);
        MFMA(uh20, bh0, C2); MFMA(uh20, bl0, C2); MFMA(ul20, bh0, C2);
        MFMA(uh21, bh1, C2); MFMA(uh21, bl1, C2); MFMA(ul21, bh1, C2);
        MFMA(uh30, bh0, C3); MFMA(uh30, bl0, C3); MFMA(ul30, bh0, C3);
        MFMA(uh31, bh1, C3); MFMA(uh31, bl1, C3); MFMA(ul31, bh1, C3);

        // attention merge for h_{t-1} (score partial sums arrived during MFMA issue)
        if (!(first && t == 0)) {
            f32x4 ssum = (s0 + s1) + (s2 + s3);
            float sc = (ssum[0] + ssum[1]) + (ssum[2] + ssum[3]);
            float mn = fmaxf(m_b, sc);
            float corr = __expf(m_b - mn);
            float p = __expf(sc - mn);
            d_b = d_b * corr + p;
            acc4 = acc4 * corr + p * h4;
            m_b = mn;
        }

        // ZX(t+1) from xc = x(t+1): independent of h, fills U-chain stalls
        buildZX(xc_h0, xc_l0, xc_h1, xc_l1);
        // rotate prefetch: xc <- xn = x(t+2); issue load x(t+3) -> xn
        xc_h0 = xn_h0; xc_l0 = xn_l0;
        if constexpr (KT == 2) { xc_h1 = xn_h1; xc_l1 = xn_l1; }
        { int tn = (t + 3 < TC) ? t + 3 : TC - 1; xload(tn, xn_h0, xn_l0, xn_h1, xn_l1); }

        // activation + state update
#pragma unroll
        for (int i = 0; i < 4; ++i) {
            float zi = sigm(C0[i]);
            float zf = sigm(C1[i]);
            float zg = fmaxf(C2[i], 0.f);
            float zo = sigm(C3[i]);
            c4[i] = fmaf(zf, c4[i], zi * zg);
            h4[i] = zo * fmaxf(c4[i], 0.f);
        }
        publish(pr ^ 1, h4);
        step_barrier();
    }

    // post-loop: final Hout store of h_{TC-1}
    if (Hhi) {
        size_t ho = (size_t)grow * (TC * HH) + (size_t)(TC - 1) * HH + cw + 4 * q;
        *reinterpret_cast<int2*>(Hhi + ho) = hs_hi;
        *reinterpret_cast<int2*>(Hlo + ho) = hs_lo;
    }
    // last chunk: merge h_{TC-1}'s score (slot 0, TC even) and emit attention output
    if (A.last[seg]) {
        const float* sp = scoreP + (0 * 16 + r) * SSTR;
        f32x4 s0 = ld4(sp), s1 = ld4(sp + 4), s2 = ld4(sp + 8), s3 = ld4(sp + 12);
        f32x4 ssum = (s0 + s1) + (s2 + s3);
        float sc = (ssum[0] + ssum[1]) + (ssum[2] + ssum[3]);
        float mn = fmaxf(m_b, sc);
        float corr = __expf(m_b - mn);
        float p = __expf(sc - mn);
        d_b = d_b * corr + p;
        acc4 = acc4 * corr + p * h4;
        m_b = mn;
        f32x4 sb = ld4(A.sbn[seg] + cw + 4 * q);
        f32x4 ab = ld4(A.abv[seg] + cw + 4 * q);
        f32x4 res;
#pragma unroll
        for (int i = 0; i < 4; ++i)
            res[i] = sb[i] * __fdividef(acc4[i], d_b) + ab[i];
        st4(A.a_out[seg] + (size_t)grow * HH + cw + 4 * q, res);
    }
    st4(A.st_c[seg]   + (size_t)grow * HH + cw + 4 * q, c4);
    st4(A.st_h[seg]   + (size_t)grow * HH + cw + 4 * q, h4);
    st4(A.st_acc[seg] + (size_t)grow * HH + cw + 4 * q, acc4);
    if (w == 0 && q == 0) { A.st_m[seg][grow] = m_b; A.st_d[seg][grow] = d_b; }
#undef LDU
#undef LDW
}

__global__ __launch_bounds__(256, 1) void rec_mfma(RecFArgs A) {
    __shared__ ushort_t hbf[2 * 2 * 16 * HSTR];   // 9.2 KB: parity x {hi,lo} x [16][72]
    __shared__ float scoreP[2 * 16 * SSTR];       // 2.5 KB: parity x row x 16 partials (+pad)
    const int seg = blockIdx.x >> 6;              // NBLK = 64
    const int b0 = (blockIdx.x & (NBLK - 1)) << 4;
    if (A.K[seg] == 32) rec_body<1>(A, seg, b0, hbf, scoreP);
    else                rec_body<2>(A, seg, b0, hbf, scoreP);
}

// ---------------- final: out[b] = db + sum_{l,j} a[l][b][j]*dw[l*64+j] ----------------
__global__ void final_kernel(const float* __restrict__ a, const float* __restrict__ dw,
                             const float* __restrict__ db, float* __restrict__ out) {
    int b = blockIdx.x * blockDim.x + threadIdx.x;
    if (b >= BB) return;
    float acc = db[0];
    for (int l = 0; l < 3; ++l)
        for (int j = 0; j < HH; ++j)
            acc += a[(l * BB + b) * HH + j] * dw[l * HH + j];
    out[b] = acc;
}

extern "C" void kernel_launch(void* const* d_in, const int* in_sizes, int n_in,
                              void* d_out, int out_size, void* d_ws, size_t ws_size,
                              hipStream_t stream) {
    (void)in_sizes; (void)n_in; (void)out_size; (void)ws_size;
    const float* x = (const float*)d_in[0];
    const float* w[3]    = {(const float*)d_in[1],  (const float*)d_in[10], (const float*)d_in[19]};
    const float* uu[3]   = {(const float*)d_in[2],  (const float*)d_in[11], (const float*)d_in[20]};
    const float* bi[3]   = {(const float*)d_in[3],  (const float*)d_in[12], (const float*)d_in[21]};
    const float* gam[3]  = {(const float*)d_in[4],  (const float*)d_in[13], (const float*)d_in[22]};
    const float* bet[3]  = {(const float*)d_in[5],  (const float*)d_in[14], (const float*)d_in[23]};
    const float* mea[3]  = {(const float*)d_in[6],  (const float*)d_in[15], (const float*)d_in[24]};
    const float* var[3]  = {(const float*)d_in[7],  (const float*)d_in[16], (const float*)d_in[25]};
    const float* atw[3]  = {(const float*)d_in[8],  (const float*)d_in[17], (const float*)d_in[26]};
    const float* atv[3]  = {(const float*)d_in[9],  (const float*)d_in[18], (const float*)d_in[27]};
    const float* dw = (const float*)d_in[28];
    const float* db = (const float*)d_in[29];

    float* ws = (float*)d_ws;
    size_t off = 0;
    // cross-layer h planes (bf16 hi/lo), parity double-buffered
    ushort_t* Hhi[2][2]; ushort_t* Hlo[2][2];
    for (int l = 0; l < 2; ++l)
        for (int p = 0; p < 2; ++p) {
            Hhi[l][p] = (ushort_t*)(ws + off); off += (size_t)BB * TC * HH / 2;
            Hlo[l][p] = (ushort_t*)(ws + off); off += (size_t)BB * TC * HH / 2;
        }
    // layer-1 input planes (bf16 hi/lo)
    ushort_t* Xhi = (ushort_t*)(ws + off); off += (size_t)BB * TT * FF / 2;
    ushort_t* Xlo = (ushort_t*)(ws + off); off += (size_t)BB * TT * FF / 2;
    float* st_h  = ws + off; off += 3 * BB * HH;
    float* st_c  = ws + off; off += 3 * BB * HH;
    float* st_ac = ws + off; off += 3 * BB * HH;
    float* st_m  = ws + off; off += 3 * BB;
    float* st_d  = ws + off; off += 3 * BB;
    float* s_ws  = ws + off; off += 3 * HH;
    float* ab_ws = ws + off; off += 3 * HH;
    float* wv_ws = ws + off; off += 3 * HH;
    float* W2p   = ws + off; off += HH * GG;
    float* W3p   = ws + off; off += HH * GG;
    float* b2p   = ws + off; off += GG;
    float* b3p   = ws + off; off += GG;
    float* a_ws  = ws + off; off += 3 * BB * HH;
    ushort_t* UFb[3]; ushort_t* WFb[3];
    for (int l = 0; l < 3; ++l) { UFb[l] = (ushort_t*)(ws + off); off += 16384; }  // 64KB each
    for (int l = 0; l < 3; ++l) { WFb[l] = (ushort_t*)(ws + off); off += 16384; }

    for (int l = 0; l < 3; ++l)
        fold1_kernel<<<1, 64, 0, stream>>>(gam[l], bet[l], mea[l], var[l], atw[l], atv[l],
                                           s_ws + l * HH, ab_ws + l * HH, wv_ws + l * HH);
    fold2_kernel<<<1, 256, 0, stream>>>(w[1], bi[1], s_ws + 0 * HH, ab_ws + 0 * HH, W2p, b2p);
    fold2_kernel<<<1, 256, 0, stream>>>(w[2], bi[2], s_ws + 1 * HH, ab_ws + 1 * HH, W3p, b3p);
    init_kernel<<<(3 * BB * HH + 255) / 256, 256, 0, stream>>>(st_h, st_c, st_ac, st_m, st_d);

    // pre-build bf16 weight fragments and x planes
    for (int l = 0; l < 3; ++l)
        prep_frags<<<64, 256, 0, stream>>>(uu[l], 2, UFb[l]);
    prep_frags<<<32, 256, 0, stream>>>(w[0], 1, WFb[0]);
    prep_frags<<<64, 256, 0, stream>>>(W2p, 2, WFb[1]);
    prep_frags<<<64, 256, 0, stream>>>(W3p, 2, WFb[2]);
    {
        int n4 = BB * TT * FF / 4;
        prep_planes<<<(n4 + 255) / 256, 256, 0, stream>>>(x, Xhi, Xlo, n4);
    }

    const float* bl[3] = {bi[0], b2p, b3p};

    // software pipeline: at step s, layer l processes chunk s-l
    for (int s = 0; s <= NCHUNK - 1 + 2; ++s) {
        RecFArgs ra;
        int nseg = 0;
        for (int l = 0; l < 3; ++l) {
            int cpos = s - l;
            if (cpos < 0 || cpos >= NCHUNK) continue;
            if (l == 0) {
                ra.xhi[nseg] = Xhi + (size_t)cpos * TC * FF;
                ra.xlo[nseg] = Xlo + (size_t)cpos * TC * FF;
                ra.sB[nseg] = (long)TT * FF;
                ra.sT[nseg] = FF;
                ra.K[nseg] = 32;
            } else {
                int par = (s & 1) ^ 1;               // written by layer l-1 at step s-1
                ra.xhi[nseg] = Hhi[l - 1][par];
                ra.xlo[nseg] = Hlo[l - 1][par];
                ra.sB[nseg] = (long)TC * HH;
                ra.sT[nseg] = HH;
                ra.K[nseg] = 64;
            }
            ra.UF[nseg] = UFb[l]; ra.WF[nseg] = WFb[l]; ra.bias[nseg] = bl[l];
            ra.Hhi[nseg] = (l < 2) ? Hhi[l][s & 1] : (ushort_t*)0;
            ra.Hlo[nseg] = (l < 2) ? Hlo[l][s & 1] : (ushort_t*)0;
            ra.st_h[nseg] = st_h + l * BB * HH;
            ra.st_c[nseg] = st_c + l * BB * HH;
            ra.st_acc[nseg] = st_ac + l * BB * HH;
            ra.st_m[nseg] = st_m + l * BB;
            ra.st_d[nseg] = st_d + l * BB;
            ra.wv[nseg]  = wv_ws + l * HH;
            ra.abv[nseg] = ab_ws + l * HH;
            ra.sbn[nseg] = s_ws + l * HH;
            ra.a_out[nseg] = a_ws + l * BB * HH;
            ra.last[nseg]  = (cpos == NCHUNK - 1) ? 1 : 0;
            ra.first[nseg] = (cpos == 0) ? 1 : 0;
            ++nseg;
        }
        if (!nseg) continue;
        rec_mfma<<<nseg * NBLK, 256, 0, stream>>>(ra);
    }
    final_kernel<<<(BB + 255) / 256, 256, 0, stream>>>(a_ws, dw, db, (float*)d_out);
}